// Round 1
// 729.245 us; speedup vs baseline: 1.0934x; 1.0934x over previous
//
#include <hip/hip_runtime.h>
#include <math.h>

#define BB 8
#define TT 256
#define UU 64
#define U1 65
#define VV 1024

#define DD 320                 // number of anti-diagonals stored: t+u in [0, 319]
#define BSTRIDE_BLANK (DD*U1)  // 20800 floats per batch
#define BSTRIDE_LAB   (DD*UU)  // 20480 floats per batch

#define LOG2E 1.4426950408889634f
#define LN2   0.6931471805599453f

// ---------------------------------------------------------------------------
// Kernel 1: per (b,t,u) row of 1024 logits, compute logsumexp and emit into
// SKEWED (anti-diagonal-major) layouts, pre-scaled into BASE-2 log domain so
// the DP kernel's serial chain uses native v_exp_f32/v_log_f32 directly:
//   blankD[b][t+u][u] = (logits[b,t,u,0]      - lse) * log2(e)
//   labD  [b][t+u][u] = (logits[b,t,u,y[b,u]] - lse) * log2(e)   (u < UU)
// One wave (64 lanes) per row; 4 coalesced float4 loads per lane.
// ---------------------------------------------------------------------------
__global__ __launch_bounds__(256) void k_rowsoftmax(
    const float* __restrict__ logits,
    const int* __restrict__ y,
    float* __restrict__ blankD,
    float* __restrict__ labD)
{
    const int lane = threadIdx.x & 63;
    const int r = (blockIdx.x * blockDim.x + threadIdx.x) >> 6;   // row id
    const int b   = r / (TT * U1);
    const int rem = r - b * (TT * U1);
    const int t   = rem / U1;
    const int u   = rem - t * U1;

    const float* row = logits + (size_t)r * VV;

    // Early, independent label-logit load (lane 0 only)
    float labv = 0.f;
    if (lane == 0 && u < UU) {
        int yidx = y[b * UU + u];
        labv = row[yidx];
    }

    const float4* row4 = (const float4*)row;
    float4 x0 = row4[lane];
    float4 x1 = row4[lane + 64];
    float4 x2 = row4[lane + 128];
    float4 x3 = row4[lane + 192];

    // Pass 1: max
    float m = fmaxf(fmaxf(fmaxf(x0.x, x0.y), fmaxf(x0.z, x0.w)),
                    fmaxf(fmaxf(x1.x, x1.y), fmaxf(x1.z, x1.w)));
    m = fmaxf(m, fmaxf(fmaxf(fmaxf(x2.x, x2.y), fmaxf(x2.z, x2.w)),
                       fmaxf(fmaxf(x3.x, x3.y), fmaxf(x3.z, x3.w))));
    #pragma unroll
    for (int off = 32; off; off >>= 1)
        m = fmaxf(m, __shfl_xor(m, off));

    // Pass 2: sum of exp(x - m)
    float s = __expf(x0.x - m) + __expf(x0.y - m) + __expf(x0.z - m) + __expf(x0.w - m)
            + __expf(x1.x - m) + __expf(x1.y - m) + __expf(x1.z - m) + __expf(x1.w - m)
            + __expf(x2.x - m) + __expf(x2.y - m) + __expf(x2.z - m) + __expf(x2.w - m)
            + __expf(x3.x - m) + __expf(x3.y - m) + __expf(x3.z - m) + __expf(x3.w - m);
    #pragma unroll
    for (int off = 32; off; off >>= 1)
        s += __shfl_xor(s, off);

    const float lse = m + __logf(s);

    if (lane == 0) {
        const int d = t + u;
        blankD[b * BSTRIDE_BLANK + d * U1 + u] = (x0.x - lse) * LOG2E;
        if (u < UU)
            labD[b * BSTRIDE_LAB + d * UU + u] = (labv - lse) * LOG2E;
    }
}

// ---------------------------------------------------------------------------
// Kernel 2: anti-diagonal wavefront DP, one wave per batch, ONE block (512
// threads) so the final mean is a deterministic LDS reduce (no memset, no
// atomic). All values are in base-2 log domain; final result scaled by ln2.
//
// Latency fix: the data was written by softmax blocks scattered over all 8
// XCDs, so reads from this single CU see cross-XCD L2 / Infinity-Cache
// latency (~400-600 cyc). Prefetch depth 1 stalled every iteration; we use
// an 8-deep register ring (fully unrolled -> static indices -> stays in
// VGPRs) so ~8 x chain(~66 cyc) covers the latency and loads pipeline with
// counted vmcnt.
// ---------------------------------------------------------------------------
#define PF 8

__global__ __launch_bounds__(512) void k_dp(
    const float* __restrict__ blankD,
    const float* __restrict__ labD,
    const int* __restrict__ logit_lens,
    const int* __restrict__ y_lens,
    float* __restrict__ out,
    int out_floats)
{
    const int lane = threadIdx.x & 63;
    const int b    = threadIdx.x >> 6;          // wave id = batch

    const float* pb = blankD + b * BSTRIDE_BLANK;   // [320][65] skewed
    const float* pl = labD   + b * BSTRIDE_LAB;     // [320][64] skewed

    const int t_idx = logit_lens[b] - 1;        // in [127,255]
    const int u_idx = y_lens[b];                // in [32,64]
    const int u     = lane + 1;
    const int dmax  = t_idx + u_idx;            // final capture diagonal (>=159)

    // alpha0[u] = inclusive prefix sum of label[0][0..lane] = labD[lane*64+lane]
    float cur = pl[lane * (UU + 1)];
    #pragma unroll
    for (int off = 1; off < 64; off <<= 1) {
        float tv = __shfl_up(cur, off);
        if (lane >= off) cur += tv;
    }

    float a0 = 0.f;                              // lane0: alpha[t][0] running value
    const float fin_blank = pb[dmax * U1 + u_idx];
    float ll = 0.f;

    // 8-deep register ring: slot i holds data for diagonal d (rows d-1, d-2)
    float rb[PF], rl[PF], r0[PF];
    #pragma unroll
    for (int i = 0; i < PF; ++i) {
        rb[i] = pb[(1 + i) * U1 + u];    // blank[d-1][u],  d = 2+i
        rl[i] = pl[(1 + i) * UU + lane]; // label[d-1][u-1]
        r0[i] = pb[i * U1];              // blank[d-2][0]
    }

    const int niter = dmax - 1;                  // d in [2, dmax]
    const int nout  = (niter + PF - 1) / PF;
    int d = 2;
    for (int blk = 0; blk < nout; ++blk) {
        #pragma unroll
        for (int i = 0; i < PF; ++i, ++d) {
            // Prefetch diagonal d+PF (rows d+PF-1, d+PF-2), clamped to the
            // allocated 320 rows; consumption of over-clamped/garbage slots
            // is guarded by (d <= dmax) and the t-range check, exactly as the
            // 1-deep version's tail behavior.
            int pr = d + PF - 1;
            if (pr > DD - 1) pr = DD - 1;
            const float nb = pb[pr * U1 + u];
            const float nl = pl[pr * UU + lane];
            const float n0 = pb[(pr - 1) * U1];

            if (d <= dmax) {                     // wave-uniform
                a0 += r0[i];                     // a0 -> alpha[d-1][0] (base-2)

                float left = __shfl_up(cur, 1);
                if (lane == 0) left = a0;

                const int t = d - u;
                if (t >= 1 && t <= TT - 1) {
                    const float aa = cur  + rb[i];   // come-from-blank
                    const float bv = left + rl[i];   // come-from-label
                    const float mm = fmaxf(aa, bv);
                    const float df = fabsf(aa - bv);
                    cur = mm + __log2f(1.0f + exp2f(-df));   // logaddexp2
                }

                if (t == t_idx && lane == u_idx - 1)
                    ll = cur + fin_blank;
            }
            rb[i] = nb; rl[i] = nl; r0[i] = n0;
        }
    }

    // deterministic block reduce; convert back to natural log
    __shared__ float part[BB];
    if (lane == u_idx - 1) part[b] = ll * LN2;
    __syncthreads();
    if (threadIdx.x == 0) {
        float s = 0.f;
        #pragma unroll
        for (int i = 0; i < BB; ++i) s += part[i];
        out[0] = -s * (1.0f / BB);
    }
    // defensive: zero any extra output floats (replaces the old memset)
    for (int i = 1 + (int)threadIdx.x; i < out_floats; i += 512)
        out[i] = 0.f;
}

extern "C" void kernel_launch(void* const* d_in, const int* in_sizes, int n_in,
                              void* d_out, int out_size, void* d_ws, size_t ws_size,
                              hipStream_t stream) {
    const float* logits     = (const float*)d_in[0];
    const int*   logit_lens = (const int*)d_in[1];
    const int*   y          = (const int*)d_in[2];
    const int*   y_lens     = (const int*)d_in[3];
    float*       out        = (float*)d_out;

    float* blankD = (float*)d_ws;                         // B*320*65 floats
    float* labD   = blankD + BB * BSTRIDE_BLANK;          // B*320*64 floats

    const int rows = BB * TT * U1;                        // 133120
    k_rowsoftmax<<<rows / 4, 256, 0, stream>>>(logits, y, blankD, labD);
    k_dp<<<1, 512, 0, stream>>>(blankD, labD, logit_lens, y_lens, out, out_size);
}

// Round 2
// 712.726 us; speedup vs baseline: 1.1187x; 1.0232x over previous
//
#include <hip/hip_runtime.h>
#include <math.h>

#define BB 8
#define TT 256
#define UU 64
#define U1 65
#define VV 1024

#define DD 320                 // anti-diagonals stored: t+u in [0, 319]
#define BSTRIDE_BLANK (DD*U1)  // 20800 floats per batch
#define BSTRIDE_LAB   (DD*UU)  // 20480 floats per batch

#define LOG2E 1.4426950408889634f
#define LN2   0.6931471805599453f
#define SENT  0xFFFFFFFFu      // impossible output bit pattern (arith NaN = 0x7FC00000)

#define PF   12                // DP prefetch ring depth (covers IF$ ~600-700 cy latency)
#define ROWS (BB*TT*U1)        // 133120 softmax rows
#define RPB  8                 // rows per softmax block (8 waves of a 512-thread block)
#define NSMBLK (ROWS/RPB)      // 16640

// Agent-scope (cross-XCD coherent) access helpers. All producer->consumer
// traffic goes through these so visibility never depends on L2 writeback.
__device__ __forceinline__ float agload(const float* p) {
    return __hip_atomic_load((float*)p, __ATOMIC_RELAXED, __HIP_MEMORY_SCOPE_AGENT);
}
__device__ __forceinline__ void agstore(float* p, float v) {
    __hip_atomic_store(p, v, __ATOMIC_RELAXED, __HIP_MEMORY_SCOPE_AGENT);
}

// ---------------------------------------------------------------------------
// Prefill: sentinel the skewed buffers (blankD ++ labD are contiguous in ws).
// Must be device-coherent stores so DP's bypassing loads can never see the
// harness poison underneath a dirty-in-some-L2 sentinel.
// ---------------------------------------------------------------------------
__global__ __launch_bounds__(256) void k_prefill(unsigned int* ws) {
    const int i = blockIdx.x * 256 + threadIdx.x;
    const int n = BB * (BSTRIDE_BLANK + BSTRIDE_LAB);   // 330240 dwords
    if (i < n)
        __hip_atomic_store(ws + i, SENT, __ATOMIC_RELAXED, __HIP_MEMORY_SCOPE_AGENT);
}

// ---------------------------------------------------------------------------
// Fused kernel.
//  block 0            : anti-diagonal DP, 8 waves, wave b = batch b. Follows
//                       the softmax frontier via sentinel-spin; finishes ~us
//                       after the last softmax block instead of serially.
//  blocks 1..NSMBLK   : row softmax, 8 rows/block, one wave per row.
//                       Row order is t-major with batch/u minor so ALL
//                       batches' diagonal frontiers advance together.
// Outputs are written in BASE-2 log domain (native v_exp/v_log in the DP
// recurrence); final loss rescaled by ln2 once.
// ---------------------------------------------------------------------------
__global__ __launch_bounds__(512) void k_fused(
    const float* __restrict__ logits,
    const int* __restrict__ y,
    float* __restrict__ blankD,
    float* __restrict__ labD,
    const int* __restrict__ logit_lens,
    const int* __restrict__ y_lens,
    float* __restrict__ out,
    int out_floats)
{
    const int lane = threadIdx.x & 63;
    const int wv   = threadIdx.x >> 6;

    if (blockIdx.x != 0) {
        // ------------------------- softmax producer -------------------------
        const int rid = (blockIdx.x - 1) * RPB + wv;    // 0 .. ROWS-1
        const int t   = rid / (U1 * BB);
        const int rem = rid - t * (U1 * BB);
        const int u   = rem >> 3;                       // 0 .. 64
        const int b   = rem & 7;

        const float* row = logits + (size_t)((b * TT + t) * U1 + u) * VV;

        float labv = 0.f;
        if (lane == 0 && u < UU)
            labv = row[y[b * UU + u]];

        const float4* row4 = (const float4*)row;
        float4 x0 = row4[lane];
        float4 x1 = row4[lane + 64];
        float4 x2 = row4[lane + 128];
        float4 x3 = row4[lane + 192];

        float m = fmaxf(fmaxf(fmaxf(x0.x, x0.y), fmaxf(x0.z, x0.w)),
                        fmaxf(fmaxf(x1.x, x1.y), fmaxf(x1.z, x1.w)));
        m = fmaxf(m, fmaxf(fmaxf(fmaxf(x2.x, x2.y), fmaxf(x2.z, x2.w)),
                           fmaxf(fmaxf(x3.x, x3.y), fmaxf(x3.z, x3.w))));
        #pragma unroll
        for (int off = 32; off; off >>= 1)
            m = fmaxf(m, __shfl_xor(m, off));

        float s = __expf(x0.x - m) + __expf(x0.y - m) + __expf(x0.z - m) + __expf(x0.w - m)
                + __expf(x1.x - m) + __expf(x1.y - m) + __expf(x1.z - m) + __expf(x1.w - m)
                + __expf(x2.x - m) + __expf(x2.y - m) + __expf(x2.z - m) + __expf(x2.w - m)
                + __expf(x3.x - m) + __expf(x3.y - m) + __expf(x3.z - m) + __expf(x3.w - m);
        #pragma unroll
        for (int off = 32; off; off >>= 1)
            s += __shfl_xor(s, off);

        const float lse = m + __logf(s);

        if (lane == 0) {
            const int d = t + u;
            agstore(&blankD[b * BSTRIDE_BLANK + d * U1 + u], (x0.x - lse) * LOG2E);
            if (u < UU)
                agstore(&labD[b * BSTRIDE_LAB + d * UU + u], (labv - lse) * LOG2E);
        }
        return;
    }

    // --------------------------- DP consumer ----------------------------
    const int b = wv;                               // wave = batch
    const float* pb = blankD + b * BSTRIDE_BLANK;   // [320][65] skewed
    const float* pl = labD   + b * BSTRIDE_LAB;     // [320][64] skewed

    const int t_idx = logit_lens[b] - 1;            // [127,255]
    const int u_idx = y_lens[b];                    // [32,64]
    const int u     = lane + 1;
    const int dmax  = t_idx + u_idx;                // final capture diagonal

    // alpha0 prefix over labD[(s=lane, col=lane)] = (t=0, u=lane): produced by
    // the very first t-slice -> short spin.
    float cur = agload(pl + lane * (UU + 1));
    while (__any(__float_as_uint(cur) == SENT))
        cur = agload(pl + lane * (UU + 1));
    #pragma unroll
    for (int off = 1; off < 64; off <<= 1) {
        float tv = __shfl_up(cur, off);
        if (lane >= off) cur += tv;
    }

    float a0 = 0.f, llv = 0.f;

    // PF-deep register ring (fully unrolled -> static indices -> VGPRs).
    float rb[PF], rl[PF], r0[PF];
    #pragma unroll
    for (int i = 0; i < PF; ++i) {
        rb[i] = agload(pb + (1 + i) * U1 + u);      // blank[d-1][u],   d = 2+i
        rl[i] = agload(pl + (1 + i) * UU + lane);   // label[d-1][u-1]
        r0[i] = agload(pb + i * U1);                // blank[d-2][0]
    }

    const int niter = dmax - 1;                     // d in [2, dmax]
    const int nout  = (niter + PF - 1) / PF;
    int d = 2;
    for (int blk = 0; blk < nout; ++blk) {
        #pragma unroll
        for (int i = 0; i < PF; ++i, ++d) {
            int pr = d + PF - 1;                    // prefetch rows pr, pr-1
            if (pr > DD - 1) pr = DD - 1;           // clamped slots never consumed
            const float nb = agload(pb + pr * U1 + u);
            const float nl = agload(pl + pr * UU + lane);
            const float n0 = agload(pb + (pr - 1) * U1);

            if (d <= dmax) {                        // wave-uniform
                const int t = d - u;
                const bool need = (t >= 1) && (t <= TT - 1);   // element exists iff consumed
                const bool need0 = (d <= TT);       // r0 row d-2 <= 254 exists; a0 dead past d=256

                // Consume gate: spin only on elements that were/will be written.
                unsigned bad = 0;
                if (need)  bad |= (__float_as_uint(rb[i]) == SENT) |
                                  (__float_as_uint(rl[i]) == SENT);
                if (need0) bad |= (__float_as_uint(r0[i]) == SENT);
                while (__any(bad)) {
                    rb[i] = agload(pb + (d - 1) * U1 + u);
                    rl[i] = agload(pl + (d - 1) * UU + lane);
                    r0[i] = agload(pb + (d - 2) * U1);
                    bad = 0;
                    if (need)  bad |= (__float_as_uint(rb[i]) == SENT) |
                                      (__float_as_uint(rl[i]) == SENT);
                    if (need0) bad |= (__float_as_uint(r0[i]) == SENT);
                }

                if (need0) a0 += r0[i];             // a0 -> alpha[d-1][0] (base-2)

                float left = __shfl_up(cur, 1);
                if (lane == 0) left = a0;

                if (need) {
                    const float aa = cur  + rb[i];  // come-from-blank
                    const float bv = left + rl[i];  // come-from-label
                    const float mm = fmaxf(aa, bv);
                    const float df = fabsf(aa - bv);
                    cur = mm + __log2f(1.0f + exp2f(-df));     // logaddexp2
                }

                if (t == t_idx && lane == u_idx - 1)
                    llv = cur;                      // at d == dmax
            }
            rb[i] = nb; rl[i] = nl; r0[i] = n0;
        }
    }

    // final blank term: row dmax col u_idx = (t_idx, u_idx) — frontier's last row
    float fb = agload(pb + dmax * U1 + u_idx);
    while (__any(__float_as_uint(fb) == SENT))
        fb = agload(pb + dmax * U1 + u_idx);

    __shared__ float part[BB];
    if (lane == u_idx - 1) part[b] = (llv + fb) * LN2;
    __syncthreads();
    if (threadIdx.x == 0) {
        float s = 0.f;
        #pragma unroll
        for (int i = 0; i < BB; ++i) s += part[i];
        out[0] = -s * (1.0f / BB);
    }
    for (int i = 1 + (int)threadIdx.x; i < out_floats; i += 512)
        out[i] = 0.f;
}

extern "C" void kernel_launch(void* const* d_in, const int* in_sizes, int n_in,
                              void* d_out, int out_size, void* d_ws, size_t ws_size,
                              hipStream_t stream) {
    const float* logits     = (const float*)d_in[0];
    const int*   logit_lens = (const int*)d_in[1];
    const int*   y          = (const int*)d_in[2];
    const int*   y_lens     = (const int*)d_in[3];
    float*       out        = (float*)d_out;

    float* blankD = (float*)d_ws;                         // B*320*65 floats
    float* labD   = blankD + BB * BSTRIDE_BLANK;          // B*320*64 floats

    const int nsent = BB * (BSTRIDE_BLANK + BSTRIDE_LAB); // 330240 dwords
    k_prefill<<<(nsent + 255) / 256, 256, 0, stream>>>((unsigned int*)d_ws);
    k_fused<<<NSMBLK + 1, 512, 0, stream>>>(logits, y, blankD, labD,
                                            logit_lens, y_lens, out, out_size);
}